// Round 8
// baseline (86.325 us; speedup 1.0000x reference)
//
#include <hip/hip_runtime.h>
#include <math.h>

// BispectrumCalculator:
//   y = fft(target)  [B,T,N] complex
//   Bx[k,l] = y[k] * conj(y[l]) * y[(l-k) mod N]
//   source = stack([Bx.re, Bx.im], ch).mean(T)  -> [B, 2, N, N]
//   outputs: (source, target)  -> d_out = source flat (16,777,216) ++ target flat (65,536)
//
// Window model (r2-r13): harness re-poison of d_ws (257 MiB, ~46us) +
// d_out (64 MiB, ~11us) is inside the measured window; controllable slice
// (dft + bispec + gaps) ~29us of the 86us window.
//
// History: r7 = 87.1. r8 = 169 (launch_bounds min-waves hint -> 64 VGPR ->
// spills; NEVER re-add). r9/r10 = 90.9 (K=8xC=4: VGPR>128 -> idle tail).
// r11 = 86.0 (single 16 KiB swizzled ring). r12 = 85.95 (kk-outer early
// stores): IDENTICAL to r11 -> bispec is pinned on the 64 MiB write floor
// (~11-13us); LDS count (60 vs 96 reads) and store schedule don't matter.
// Do not touch bispec further.
//
// r13: dft overhaul (the only slice with modeled headroom):
//  - 8-way n-split: 1024 blocks (128bt x 8kq), 256 thr = 32 kl x 8 nh,
//    64 n/thread -> 4 waves/SIMD (2x TLP for the dependent rotor chain).
//  - sincosf 5 -> 2 per thread: seed w0 = e^{i th (k n0 mod 512)} and
//    u = e^{i th k}; w1..w3 = w0 u^j, rotor u^4 via squaring.
//  - float4 broadcast x-loads (1 uniform 16B fetch per 4-n iter).

#define NN 512
#define TT 4
#define BB 32

// bijective within each 64-entry (512 B) float2 tile
__device__ __forceinline__ int sw_idx(int idx) {
    return (idx & ~63) | ((idx & 3) << 4) | ((idx >> 2) & 15);
}

__device__ __forceinline__ float2 cmul(float2 a, float2 b) {
    return make_float2(a.x * b.x - a.y * b.y, a.x * b.y + a.y * b.x);
}

// ---------------------------------------------------------------------------
// Kernel A: Hermitian DFT-512 per (b,t).
// Grid = 128 bt x 8 kq = 1024 blocks, 256 threads = 32 kl x 8 nh.
// k = kq*32 + kl in [0,256); each thread sums n in [nh*64, nh*64+64).
// 2 sincosf seeds + cmul-derived twiddles; nh partials combined in LDS;
// nh==0 stores y[k] and conj to y[512-k]. kq==0 also computes y[256]
// (alternating sum) and copies the target row to the output tail.
// ---------------------------------------------------------------------------
__global__ __launch_bounds__(256) void dft_kernel(const float* __restrict__ x,
                                                  float2* __restrict__ y,
                                                  float* __restrict__ tail) {
    __shared__ float2 part[224];      // nh = 1..7 partials, [nh-1][kl]
    __shared__ float  salt[8];        // alternating-sum partials per nh

    int bt = blockIdx.x >> 3;
    int kq = blockIdx.x & 7;
    int kl = threadIdx.x & 31;
    int nh = threadIdx.x >> 5;
    int k  = (kq << 5) | kl;          // [0,256)
    const float* xp = x + (size_t)bt * NN;

    if (kq == 0 && nh == 0) {
        // target passthrough: 32 lanes x 4 float4 = 2 KiB row
        float4* tp = (float4*)(tail + (size_t)bt * NN);
        const float4* sp = (const float4*)xp;
        tp[kl]      = sp[kl];
        tp[kl + 32] = sp[kl + 32];
        tp[kl + 64] = sp[kl + 64];
        tp[kl + 96] = sp[kl + 96];
    }

    int n0 = nh << 6;  // 0,64,...,448
    const float tw = -2.0f * (float)M_PI / (float)NN;

    // seeds: 2 sincosf + 5 cmul
    float2 w0, u;
    {
        int m0 = (k * n0) & (NN - 1);
        sincosf(tw * (float)m0, &w0.y, &w0.x);
        sincosf(tw * (float)k,  &u.y,  &u.x);
    }
    float2 u2 = cmul(u, u);
    float2 u4 = cmul(u2, u2);
    float2 w1 = cmul(w0, u);
    float2 w2 = cmul(w0, u2);
    float2 w3 = cmul(w1, u2);
    float c4 = u4.x, s4 = u4.y;

    float2 a0 = make_float2(0.f, 0.f), a1 = a0, a2 = a0, a3 = a0;
    float sa = 0.f;  // alternating sum partial (kq==0 only)

    const float4* xp4 = (const float4*)xp;
    int i4 = n0 >> 2;

    if (kq == 0) {
        #pragma unroll 4
        for (int it = 0; it < 16; ++it) {
            float4 xv = xp4[i4 + it];         // uniform 16B broadcast fetch
            sa += (xv.x - xv.y) + (xv.z - xv.w);  // n0 even -> +,-,+,-
            a0.x += xv.x * w0.x; a0.y += xv.x * w0.y;
            a1.x += xv.y * w1.x; a1.y += xv.y * w1.y;
            a2.x += xv.z * w2.x; a2.y += xv.z * w2.y;
            a3.x += xv.w * w3.x; a3.y += xv.w * w3.y;
            float t;
            t = w0.x * c4 - w0.y * s4; w0.y = w0.x * s4 + w0.y * c4; w0.x = t;
            t = w1.x * c4 - w1.y * s4; w1.y = w1.x * s4 + w1.y * c4; w1.x = t;
            t = w2.x * c4 - w2.y * s4; w2.y = w2.x * s4 + w2.y * c4; w2.x = t;
            t = w3.x * c4 - w3.y * s4; w3.y = w3.x * s4 + w3.y * c4; w3.x = t;
        }
    } else {
        #pragma unroll 4
        for (int it = 0; it < 16; ++it) {
            float4 xv = xp4[i4 + it];
            a0.x += xv.x * w0.x; a0.y += xv.x * w0.y;
            a1.x += xv.y * w1.x; a1.y += xv.y * w1.y;
            a2.x += xv.z * w2.x; a2.y += xv.z * w2.y;
            a3.x += xv.w * w3.x; a3.y += xv.w * w3.y;
            float t;
            t = w0.x * c4 - w0.y * s4; w0.y = w0.x * s4 + w0.y * c4; w0.x = t;
            t = w1.x * c4 - w1.y * s4; w1.y = w1.x * s4 + w1.y * c4; w1.x = t;
            t = w2.x * c4 - w2.y * s4; w2.y = w2.x * s4 + w2.y * c4; w2.x = t;
            t = w3.x * c4 - w3.y * s4; w3.y = w3.x * s4 + w3.y * c4; w3.x = t;
        }
    }

    float re = (a0.x + a1.x) + (a2.x + a3.x);
    float im = (a0.y + a1.y) + (a2.y + a3.y);

    if (nh) {
        part[((nh - 1) << 5) + kl] = make_float2(re, im);
    }
    if (kq == 0 && kl == 0) {
        salt[nh] = sa;
    }
    __syncthreads();

    if (nh == 0) {
        float rr = re, ii = im;
        #pragma unroll
        for (int i = 0; i < 7; ++i) {
            float2 p = part[(i << 5) + kl];
            rr += p.x; ii += p.y;
        }
        float2* yb = y + (size_t)bt * NN;
        yb[k] = make_float2(rr, ii);
        if (k != 0) {
            yb[NN - k] = make_float2(rr, -ii);   // Hermitian mirror
        }
        if (kq == 0 && kl == 0) {
            float s = ((salt[0] + salt[1]) + (salt[2] + salt[3]))
                    + ((salt[4] + salt[5]) + (salt[6] + salt[7]));
            yb[NN / 2] = make_float2(s, 0.f);
        }
    }
}

// ---------------------------------------------------------------------------
// Kernel B: bispectrum (byte-identical to r12). Grid = B * 64 = 2048
// blocks x 256 threads. Block = one b, 8 consecutive k-rows, all 512 cols.
// Thread = 4 rows x 4 ADJACENT cols. kk-OUTER / t-INNER with immediate
// per-row stores. bb[t][c] hoisted to regs; per kk only its 4-wide slice
// of the 7-window is read; av is a wave-uniform broadcast. Single swizzled
// 16 KiB ring, wrap folded into precomputed indices:
//     sw(idx) = (idx&~63) | ((idx&3)<<4) | ((idx>>2)&15)
// ---------------------------------------------------------------------------
__global__ __launch_bounds__(256) void bispec_kernel(const float2* __restrict__ y,
                                                     float* __restrict__ out) {
    __shared__ float2 ring[TT * NN];  // 16 KiB, swizzled, single copy

    int b   = blockIdx.x >> 6;
    int kb  = blockIdx.x & 63;   // 8-row group
    int tid = threadIdx.x;

    // stage y[b] -> swizzled ring (global: [t][256] float4)
    const float4* src = (const float4*)(y + (size_t)b * TT * NN);
    #pragma unroll
    for (int i = 0; i < 4; ++i) {
        int g = tid + 256 * i;          // [0,1024)
        int t = g >> 8;
        int j = g & 255;                // float4 index within t-row (512 float2)
        float4 v = src[g];
        int s0 = sw_idx((t << 9) + 2 * j);   // 2j even -> sw(2j+1)=sw(2j)+16
        ring[s0]      = make_float2(v.x, v.y);
        ring[s0 + 16] = make_float2(v.z, v.w);
    }
    __syncthreads();

    int kg    = tid >> 7;            // wave-uniform (waves 0,1 -> 0; 2,3 -> 1)
    int ll    = tid & 127;
    int l0    = ll << 2;             // 4 adjacent columns l0..l0+3
    int kbase = (kb << 3) | (kg << 2);  // this thread's 4 rows (kbase%4==0)

    // swizzled t=0 indices (wrap folded in), reused across t via +t*512
    int w0 = (l0 - kbase - 3) & (NN - 1);  // window start
    int swj[7];
    #pragma unroll
    for (int j = 0; j < 7; ++j) swj[j] = sw_idx((w0 + j) & (NN - 1));
    int sa0 = sw_idx(kbase);  // kbase%4==0 -> av[kk] at sa0 + (kk<<4)
    int sb0 = sw_idx(l0);     // l0%4==0   -> bb[c]  at sb0 + (c<<4)

    // hoist kk-invariant conj-source values: bb[t][c] (32 VGPR)
    float2 bbr[TT][4];
    #pragma unroll
    for (int t = 0; t < TT; ++t)
        #pragma unroll
        for (int c = 0; c < 4; ++c)
            bbr[t][c] = ring[(t << 9) + sb0 + (c << 4)];

    float* outb = out + (size_t)b * 2 * NN * NN;

    #pragma unroll
    for (int kk = 0; kk < 4; ++kk) {
        float r[4] = {0.f, 0.f, 0.f, 0.f};
        float q[4] = {0.f, 0.f, 0.f, 0.f};

        #pragma unroll
        for (int t = 0; t < TT; ++t) {
            const float2* rt = ring + (t << 9);
            float2 a  = rt[sa0 + (kk << 4)];   // wave-uniform broadcast
            float2 cw0 = rt[swj[3 - kk + 0]];  // lane-spread, conflict-free
            float2 cw1 = rt[swj[3 - kk + 1]];
            float2 cw2 = rt[swj[3 - kk + 2]];
            float2 cw3 = rt[swj[3 - kk + 3]];
            float2 cwv[4] = {cw0, cw1, cw2, cw3};
            #pragma unroll
            for (int c = 0; c < 4; ++c) {
                float2 cv = cwv[c];           // = y_t[(l0+c - kbase-kk) mod 512]
                float2 bv = bbr[t][c];        // = y_t[l0+c]
                float ur = a.x * cv.x - a.y * cv.y;
                float ui = a.x * cv.y + a.y * cv.x;
                r[c] += ur * bv.x + ui * bv.y;   // Re(a*cv*conj(bv))
                q[c] += ui * bv.x - ur * bv.y;   // Im(a*cv*conj(bv))
            }
        }

        // store this k-row immediately -> overlaps later kk's compute
        size_t rk = (size_t)(kbase + kk) * NN + l0;
        float4 vr = make_float4(r[0] * 0.25f, r[1] * 0.25f,
                                r[2] * 0.25f, r[3] * 0.25f);
        float4 vq = make_float4(q[0] * 0.25f, q[1] * 0.25f,
                                q[2] * 0.25f, q[3] * 0.25f);
        *(float4*)(outb + rk)                   = vr;  // real ch
        *(float4*)(outb + (size_t)NN * NN + rk) = vq;  // imag ch
    }
}

extern "C" void kernel_launch(void* const* d_in, const int* in_sizes, int n_in,
                              void* d_out, int out_size, void* d_ws, size_t ws_size,
                              hipStream_t stream) {
    const float* target = (const float*)d_in[0];
    float* out = (float*)d_out;
    // workspace: y spectrum, B*T*N complex64 = 512 KiB
    float2* y = (float2*)d_ws;
    float* tail = out + (size_t)BB * 2 * NN * NN;  // target passthrough

    dft_kernel<<<BB * TT * 8, 256, 0, stream>>>(target, y, tail);
    bispec_kernel<<<BB * 64, 256, 0, stream>>>(y, out);
}